// Round 1
// baseline (1860.449 us; speedup 1.0000x reference)
//
#include <hip/hip_runtime.h>
#include <float.h>
#include <math.h>

#define BB 8
#define LL 2048
#define DD 512
#define HH 8
#define DEPTH 64
#define TOPK 15

// C[r, c] = sum_k X[r,k] W[k,c] + bias[c], stored transposed per-head:
// outT[((b*HH + h)*DEPTH + dd)*LL + l] where r = b*LL + l, c = h*DEPTH + dd
__global__ __launch_bounds__(256) void proj_gemm_t(const float* __restrict__ X,
                                                   const float* __restrict__ W,
                                                   const float* __restrict__ bias,
                                                   float* __restrict__ outT) {
    __shared__ float As[64][17];
    __shared__ float Bs[16][64];
    const int tid = threadIdx.x;
    const int tx = tid & 15, ty = tid >> 4;
    const int r0 = blockIdx.y * 64;
    const int c0 = blockIdx.x * 64;
    float acc[4][4] = {};
    for (int kk0 = 0; kk0 < DD; kk0 += 16) {
#pragma unroll
        for (int p = 0; p < 4; ++p) {
            int a = tid + 256 * p;
            int ar = a >> 4, ac = a & 15;
            As[ar][ac] = X[(size_t)(r0 + ar) * DD + kk0 + ac];
        }
#pragma unroll
        for (int p = 0; p < 4; ++p) {
            int bI = tid + 256 * p;
            int br = bI >> 6, bc = bI & 63;
            Bs[br][bc] = W[(size_t)(kk0 + br) * DD + c0 + bc];
        }
        __syncthreads();
#pragma unroll
        for (int kk = 0; kk < 16; ++kk) {
            float av[4];
#pragma unroll
            for (int i = 0; i < 4; ++i) av[i] = As[ty * 4 + i][kk];
            const float4 b4 = *reinterpret_cast<const float4*>(&Bs[kk][tx * 4]);
#pragma unroll
            for (int i = 0; i < 4; ++i) {
                acc[i][0] += av[i] * b4.x;
                acc[i][1] += av[i] * b4.y;
                acc[i][2] += av[i] * b4.z;
                acc[i][3] += av[i] * b4.w;
            }
        }
        __syncthreads();
    }
    const int h = c0 >> 6;  // c0 is a multiple of 64, so one head per block-col
#pragma unroll
    for (int i = 0; i < 4; ++i) {
        int r = r0 + ty * 4 + i;
        int b = r >> 11, l = r & (LL - 1);
#pragma unroll
        for (int j = 0; j < 4; ++j) {
            int dd = tx * 4 + j;
            outT[((size_t)(b * HH + h) * DEPTH + dd) * LL + l] = acc[i][j] + bias[c0 + dd];
        }
    }
}

// One block per (b,h,depth) row. Computes circular correlation
// R[tau] = sum_s k[s] * q[(s+tau) mod L], top-15, softmax, then
// delays[t] = sum_i corr[i] * q[(t + idx[i]) mod L], overwriting the kt row.
__global__ __launch_bounds__(256) void corr_kernel(const float* __restrict__ qt,
                                                   float* __restrict__ ktDelays) {
    __shared__ float q_s[LL];
    __shared__ float k_s[LL];
    __shared__ float R[LL];
    __shared__ float sv[256];
    __shared__ int si[256];
    __shared__ float topw[TOPK];
    __shared__ int topi[TOPK];
    __shared__ float corr_s[TOPK];
    const int tid = threadIdx.x;
    const size_t base = (size_t)blockIdx.x * LL;

#pragma unroll
    for (int j = 0; j < 8; ++j) {
        q_s[tid + 256 * j] = qt[base + tid + 256 * j];
        k_s[tid + 256 * j] = ktDelays[base + tid + 256 * j];
    }
    __syncthreads();

    // direct circular correlation: 8 taus per thread, ILP across j
    {
        float acc[8] = {};
        for (int s = 0; s < LL; ++s) {
            float kv = k_s[s];
#pragma unroll
            for (int j = 0; j < 8; ++j)
                acc[j] += kv * q_s[(s + tid + 256 * j) & (LL - 1)];
        }
#pragma unroll
        for (int j = 0; j < 8; ++j) R[tid + 256 * j] = acc[j];
    }
    __syncthreads();

    // top-15 via repeated argmax (tree reduce), mask with -FLT_MAX
    for (int it = 0; it < TOPK; ++it) {
        float best = -FLT_MAX;
        int bidx = 0;
#pragma unroll
        for (int j = 0; j < 8; ++j) {
            int tau = tid + 256 * j;
            float v = R[tau];
            if (v > best) { best = v; bidx = tau; }
        }
        sv[tid] = best;
        si[tid] = bidx;
        __syncthreads();
        for (int off = 128; off > 0; off >>= 1) {
            if (tid < off) {
                float v2 = sv[tid + off];
                int i2 = si[tid + off];
                if (v2 > sv[tid] || (v2 == sv[tid] && i2 < si[tid])) {
                    sv[tid] = v2;
                    si[tid] = i2;
                }
            }
            __syncthreads();
        }
        if (tid == 0) {
            topw[it] = sv[0];
            topi[it] = si[0];
            R[si[0]] = -FLT_MAX;
        }
        __syncthreads();
    }

    // softmax over the 15 weights
    if (tid == 0) {
        float m = topw[0];
        for (int i = 1; i < TOPK; ++i) m = fmaxf(m, topw[i]);
        float s = 0.f;
        for (int i = 0; i < TOPK; ++i) {
            float e = expf(topw[i] - m);
            corr_s[i] = e;
            s += e;
        }
        float inv = 1.f / s;
        for (int i = 0; i < TOPK; ++i) corr_s[i] *= inv;
    }
    __syncthreads();

    // aggregation (gathers from q, per reference), overwrite kt row
    for (int j = 0; j < 8; ++j) {
        int t = tid + 256 * j;
        float acc = 0.f;
#pragma unroll
        for (int i = 0; i < TOPK; ++i)
            acc += corr_s[i] * q_s[(t + topi[i]) & (LL - 1)];
        ktDelays[base + t] = acc;
    }
}

// out[r, c] = sum_k Z[r,k] Wo[k,c] + bo[c], where Z is read from the
// transposed [B,H,DEPTH,L] delays buffer.
__global__ __launch_bounds__(256) void out_gemm(const float* __restrict__ Zt,
                                                const float* __restrict__ W,
                                                const float* __restrict__ bias,
                                                float* __restrict__ out) {
    __shared__ float As[64][17];
    __shared__ float Bs[16][64];
    const int tid = threadIdx.x;
    const int tx = tid & 15, ty = tid >> 4;
    const int r0 = blockIdx.y * 64;
    const int c0 = blockIdx.x * 64;
    const int b = r0 >> 11, l0 = r0 & (LL - 1);  // 64-row tile never crosses batch
    float acc[4][4] = {};
    for (int kk0 = 0; kk0 < DD; kk0 += 16) {
#pragma unroll
        for (int p = 0; p < 4; ++p) {
            int a = tid + 256 * p;
            int al = a & 63, ac = a >> 6;  // l-offset fastest for coalescing
            int c = kk0 + ac;
            int h = c >> 6, dd = c & 63;
            As[al][ac] = Zt[((size_t)(b * HH + h) * DEPTH + dd) * LL + l0 + al];
        }
#pragma unroll
        for (int p = 0; p < 4; ++p) {
            int bI = tid + 256 * p;
            int br = bI >> 6, bc = bI & 63;
            Bs[br][bc] = W[(size_t)(kk0 + br) * DD + c0 + bc];
        }
        __syncthreads();
#pragma unroll
        for (int kk = 0; kk < 16; ++kk) {
            float av[4];
#pragma unroll
            for (int i = 0; i < 4; ++i) av[i] = As[ty * 4 + i][kk];
            const float4 b4 = *reinterpret_cast<const float4*>(&Bs[kk][tx * 4]);
#pragma unroll
            for (int i = 0; i < 4; ++i) {
                acc[i][0] += av[i] * b4.x;
                acc[i][1] += av[i] * b4.y;
                acc[i][2] += av[i] * b4.z;
                acc[i][3] += av[i] * b4.w;
            }
        }
        __syncthreads();
    }
#pragma unroll
    for (int i = 0; i < 4; ++i) {
        int r = r0 + ty * 4 + i;
        float4 o;
        o.x = acc[i][0] + bias[c0 + tx * 4 + 0];
        o.y = acc[i][1] + bias[c0 + tx * 4 + 1];
        o.z = acc[i][2] + bias[c0 + tx * 4 + 2];
        o.w = acc[i][3] + bias[c0 + tx * 4 + 3];
        *reinterpret_cast<float4*>(&out[(size_t)r * DD + c0 + tx * 4]) = o;
    }
}

extern "C" void kernel_launch(void* const* d_in, const int* in_sizes, int n_in,
                              void* d_out, int out_size, void* d_ws, size_t ws_size,
                              hipStream_t stream) {
    const float* q  = (const float*)d_in[0];
    const float* k  = (const float*)d_in[1];
    // d_in[2] = v (unused by the reference aggregation)
    const float* Wq = (const float*)d_in[3];
    const float* bq = (const float*)d_in[4];
    const float* Wk = (const float*)d_in[5];
    const float* bk = (const float*)d_in[6];
    // d_in[7], d_in[8] = Wv, bv (unused)
    const float* Wo = (const float*)d_in[9];
    const float* bo = (const float*)d_in[10];
    float* out = (float*)d_out;

    float* qt = (float*)d_ws;                                  // [B,H,DEPTH,L] fp32
    float* kt = qt + (size_t)BB * HH * DEPTH * LL;             // [B,H,DEPTH,L], reused as delays

    dim3 blk(256);
    dim3 g1(DD / 64, (BB * LL) / 64);
    proj_gemm_t<<<g1, blk, 0, stream>>>(q, Wq, bq, qt);
    proj_gemm_t<<<g1, blk, 0, stream>>>(k, Wk, bk, kt);
    corr_kernel<<<dim3(BB * HH * DEPTH), blk, 0, stream>>>(qt, kt);
    out_gemm<<<g1, blk, 0, stream>>>(kt, Wo, bo, out);
}

// Round 2
// 610.883 us; speedup vs baseline: 3.0455x; 3.0455x over previous
//
#include <hip/hip_runtime.h>
#include <float.h>
#include <math.h>

#define BB 8
#define LL 2048
#define NN 2048
#define LOG2N 11
#define DD 512
#define HH 8
#define DEPTH 64
#define TOPK 15

__device__ __forceinline__ float2 cmul(float2 a, float2 b) {
    return make_float2(a.x * b.x - a.y * b.y, a.x * b.y + a.y * b.x);
}
__device__ __forceinline__ float2 cmulc(float2 a, float2 b) {  // a * conj(b)
    return make_float2(a.x * b.x + a.y * b.y, a.y * b.x - a.x * b.y);
}

// C[r, c] = sum_k X[r,k] W[k,c] + bias[c], stored transposed per-head:
// outT[((b*HH + h)*DEPTH + dd)*LL + l] where r = b*LL + l, c = h*DEPTH + dd
__global__ __launch_bounds__(256) void proj_gemm_t(const float* __restrict__ X,
                                                   const float* __restrict__ W,
                                                   const float* __restrict__ bias,
                                                   float* __restrict__ outT) {
    __shared__ float As[64][17];
    __shared__ float Bs[16][64];
    const int tid = threadIdx.x;
    const int tx = tid & 15, ty = tid >> 4;
    const int r0 = blockIdx.y * 64;
    const int c0 = blockIdx.x * 64;
    float acc[4][4] = {};
    for (int kk0 = 0; kk0 < DD; kk0 += 16) {
#pragma unroll
        for (int p = 0; p < 4; ++p) {
            int a = tid + 256 * p;
            int ar = a >> 4, ac = a & 15;
            As[ar][ac] = X[(size_t)(r0 + ar) * DD + kk0 + ac];
        }
#pragma unroll
        for (int p = 0; p < 4; ++p) {
            int bI = tid + 256 * p;
            int br = bI >> 6, bc = bI & 63;
            Bs[br][bc] = W[(size_t)(kk0 + br) * DD + c0 + bc];
        }
        __syncthreads();
#pragma unroll
        for (int kk = 0; kk < 16; ++kk) {
            float av[4];
#pragma unroll
            for (int i = 0; i < 4; ++i) av[i] = As[ty * 4 + i][kk];
            const float4 b4 = *reinterpret_cast<const float4*>(&Bs[kk][tx * 4]);
#pragma unroll
            for (int i = 0; i < 4; ++i) {
                acc[i][0] += av[i] * b4.x;
                acc[i][1] += av[i] * b4.y;
                acc[i][2] += av[i] * b4.z;
                acc[i][3] += av[i] * b4.w;
            }
        }
        __syncthreads();
    }
    const int h = c0 >> 6;
#pragma unroll
    for (int i = 0; i < 4; ++i) {
        int r = r0 + ty * 4 + i;
        int b = r >> 11, l = r & (LL - 1);
#pragma unroll
        for (int j = 0; j < 4; ++j) {
            int dd = tx * 4 + j;
            outT[((size_t)(b * HH + h) * DEPTH + dd) * LL + l] = acc[i][j] + bias[c0 + dd];
        }
    }
}

// One block per (b,h,depth) row. FFT-based circular correlation:
// z = q + i*k; Z = FFT(z); unpack Q,K; S = Q*conj(K); R = IFFT(S).real/N.
// Then top-15 (register-resident R), softmax, aggregation from q_s.
__global__ __launch_bounds__(256) void corr_fft_kernel(const float* __restrict__ qt,
                                                       float* __restrict__ ktDelays) {
    __shared__ float2 z[NN];        // 16 KB
    __shared__ float2 tw[NN / 2];   // 8 KB: tw[j] = exp(-2*pi*i*j/N)
    __shared__ float q_s[NN];       // 8 KB
    __shared__ float sv[4];
    __shared__ int si[4];
    __shared__ float topw[TOPK];
    __shared__ int topi[TOPK];
    __shared__ float corr_s[TOPK];
    __shared__ int bcast_i;

    const int tid = threadIdx.x;
    const int lane = tid & 63, wid = tid >> 6;
    const size_t base = (size_t)blockIdx.x * NN;

#pragma unroll
    for (int u = 0; u < 8; ++u) {
        int t = tid + 256 * u;
        float qv = qt[base + t];
        float kv = ktDelays[base + t];
        z[t] = make_float2(qv, kv);
        q_s[t] = qv;
    }
#pragma unroll
    for (int u = 0; u < 4; ++u) {
        int j = tid + 256 * u;
        float ang = -6.28318530717958647692f * (float)j / (float)NN;
        float sn, cs;
        __sincosf(ang, &sn, &cs);
        tw[j] = make_float2(cs, sn);
    }
    __syncthreads();

    // ---- forward DIF FFT (natural in -> bit-reversed out) ----
    for (int h = NN / 2; h >= 1; h >>= 1) {
        const int step = (NN / 2) / h;
#pragma unroll 4
        for (int u = 0; u < 4; ++u) {
            int b = tid + 256 * u;
            int pos = b & (h - 1);
            int i0 = ((b ^ pos) << 1) | pos;  // (b & ~(h-1))*2 + pos
            int i1 = i0 + h;
            float2 a = z[i0], c = z[i1];
            float2 s = make_float2(a.x + c.x, a.y + c.y);
            float2 d = make_float2(a.x - c.x, a.y - c.y);
            z[i0] = s;
            z[i1] = cmul(d, tw[pos * step]);
        }
        __syncthreads();
    }

    // ---- Hermitian unpack + pointwise S = Q * conj(K), in bit-reversed slots ----
    {
        float2 Sreg[8];
        int addr[8];
#pragma unroll
        for (int u = 0; u < 8; ++u) {
            int f = tid + 256 * u;
            int pf = (int)(__brev((unsigned)f) >> (32 - LOG2N));
            int pmf = (int)(__brev((unsigned)((NN - f) & (NN - 1))) >> (32 - LOG2N));
            float2 Zf = z[pf], Zm = z[pmf];
            float2 Qf = make_float2(0.5f * (Zf.x + Zm.x), 0.5f * (Zf.y - Zm.y));
            float2 Dm = make_float2(Zf.x - Zm.x, Zf.y + Zm.y);   // Zf - conj(Zm)
            float2 Kf = make_float2(0.5f * Dm.y, -0.5f * Dm.x);  // -0.5i * Dm
            Sreg[u] = cmulc(Qf, Kf);
            addr[u] = pf;
        }
        __syncthreads();
#pragma unroll
        for (int u = 0; u < 8; ++u) z[addr[u]] = Sreg[u];
        __syncthreads();
    }

    // ---- inverse DIT FFT (bit-reversed in -> natural out), conj twiddles ----
    for (int h = 1; h <= NN / 4; h <<= 1) {
        const int step = (NN / 2) / h;
#pragma unroll 4
        for (int u = 0; u < 4; ++u) {
            int b = tid + 256 * u;
            int pos = b & (h - 1);
            int i0 = ((b ^ pos) << 1) | pos;
            int i1 = i0 + h;
            float2 w = tw[pos * step];
            w.y = -w.y;
            float2 t = cmul(z[i1], w);
            float2 a = z[i0];
            z[i0] = make_float2(a.x + t.x, a.y + t.y);
            z[i1] = make_float2(a.x - t.x, a.y - t.y);
        }
        __syncthreads();
    }
    // final stage h = N/2 straight into registers: thread owns tau = tid + 256*w
    float r[8];
#pragma unroll
    for (int u = 0; u < 4; ++u) {
        int b = tid + 256 * u;
        float2 w = tw[b];
        w.y = -w.y;
        float2 t = cmul(z[b + NN / 2], w);
        float2 a = z[b];
        r[u] = (a.x + t.x) * (1.0f / NN);
        r[u + 4] = (a.x - t.x) * (1.0f / NN);
    }

    // ---- top-15: register-local scan + wave shfl reduce + cross-wave merge ----
    for (int it = 0; it < TOPK; ++it) {
        float best = -FLT_MAX;
        int bi = 0x7fffffff;
#pragma unroll
        for (int w = 0; w < 8; ++w) {
            float v = r[w];
            int idx = tid + 256 * w;
            if (v > best || (v == best && idx < bi)) { best = v; bi = idx; }
        }
#pragma unroll
        for (int off = 32; off >= 1; off >>= 1) {
            float ov = __shfl_xor(best, off);
            int oi = __shfl_xor(bi, off);
            if (ov > best || (ov == best && oi < bi)) { best = ov; bi = oi; }
        }
        if (lane == 0) { sv[wid] = best; si[wid] = bi; }
        __syncthreads();
        if (tid == 0) {
            float bb = sv[0];
            int bbi = si[0];
            for (int wv = 1; wv < 4; ++wv) {
                if (sv[wv] > bb || (sv[wv] == bb && si[wv] < bbi)) { bb = sv[wv]; bbi = si[wv]; }
            }
            topw[it] = bb;
            topi[it] = bbi;
            bcast_i = bbi;
        }
        __syncthreads();
        int widx = bcast_i;
#pragma unroll
        for (int w = 0; w < 8; ++w)
            if (tid + 256 * w == widx) r[w] = -FLT_MAX;
    }

    // ---- softmax over 15 weights ----
    if (tid == 0) {
        float m = topw[0];
        for (int i = 1; i < TOPK; ++i) m = fmaxf(m, topw[i]);
        float ssum = 0.f;
        for (int i = 0; i < TOPK; ++i) {
            float e = expf(topw[i] - m);
            corr_s[i] = e;
            ssum += e;
        }
        float inv = 1.f / ssum;
        for (int i = 0; i < TOPK; ++i) corr_s[i] *= inv;
    }
    __syncthreads();

    // ---- aggregation (gathers from q), overwrite kt row ----
#pragma unroll
    for (int w = 0; w < 8; ++w) {
        int t = tid + 256 * w;
        float acc = 0.f;
#pragma unroll
        for (int i = 0; i < TOPK; ++i)
            acc += corr_s[i] * q_s[(t + topi[i]) & (NN - 1)];
        ktDelays[base + t] = acc;
    }
}

// out[r, c] = sum_k Z[r,k] Wo[k,c] + bo[c], Z read from transposed delays.
__global__ __launch_bounds__(256) void out_gemm(const float* __restrict__ Zt,
                                                const float* __restrict__ W,
                                                const float* __restrict__ bias,
                                                float* __restrict__ out) {
    __shared__ float As[64][17];
    __shared__ float Bs[16][64];
    const int tid = threadIdx.x;
    const int tx = tid & 15, ty = tid >> 4;
    const int r0 = blockIdx.y * 64;
    const int c0 = blockIdx.x * 64;
    const int b = r0 >> 11, l0 = r0 & (LL - 1);
    float acc[4][4] = {};
    for (int kk0 = 0; kk0 < DD; kk0 += 16) {
#pragma unroll
        for (int p = 0; p < 4; ++p) {
            int a = tid + 256 * p;
            int al = a & 63, ac = a >> 6;
            int c = kk0 + ac;
            int h = c >> 6, dd = c & 63;
            As[al][ac] = Zt[((size_t)(b * HH + h) * DEPTH + dd) * LL + l0 + al];
        }
#pragma unroll
        for (int p = 0; p < 4; ++p) {
            int bI = tid + 256 * p;
            int br = bI >> 6, bc = bI & 63;
            Bs[br][bc] = W[(size_t)(kk0 + br) * DD + c0 + bc];
        }
        __syncthreads();
#pragma unroll
        for (int kk = 0; kk < 16; ++kk) {
            float av[4];
#pragma unroll
            for (int i = 0; i < 4; ++i) av[i] = As[ty * 4 + i][kk];
            const float4 b4 = *reinterpret_cast<const float4*>(&Bs[kk][tx * 4]);
#pragma unroll
            for (int i = 0; i < 4; ++i) {
                acc[i][0] += av[i] * b4.x;
                acc[i][1] += av[i] * b4.y;
                acc[i][2] += av[i] * b4.z;
                acc[i][3] += av[i] * b4.w;
            }
        }
        __syncthreads();
    }
#pragma unroll
    for (int i = 0; i < 4; ++i) {
        int r = r0 + ty * 4 + i;
        float4 o;
        o.x = acc[i][0] + bias[c0 + tx * 4 + 0];
        o.y = acc[i][1] + bias[c0 + tx * 4 + 1];
        o.z = acc[i][2] + bias[c0 + tx * 4 + 2];
        o.w = acc[i][3] + bias[c0 + tx * 4 + 3];
        *reinterpret_cast<float4*>(&out[(size_t)r * DD + c0 + tx * 4]) = o;
    }
}

extern "C" void kernel_launch(void* const* d_in, const int* in_sizes, int n_in,
                              void* d_out, int out_size, void* d_ws, size_t ws_size,
                              hipStream_t stream) {
    const float* q = (const float*)d_in[0];
    const float* k = (const float*)d_in[1];
    const float* Wq = (const float*)d_in[3];
    const float* bq = (const float*)d_in[4];
    const float* Wk = (const float*)d_in[5];
    const float* bk = (const float*)d_in[6];
    const float* Wo = (const float*)d_in[9];
    const float* bo = (const float*)d_in[10];
    float* out = (float*)d_out;

    float* qt = (float*)d_ws;                       // [B,H,DEPTH,L] fp32
    float* kt = qt + (size_t)BB * HH * DEPTH * LL;  // [B,H,DEPTH,L], reused as delays

    dim3 blk(256);
    dim3 g1(DD / 64, (BB * LL) / 64);
    proj_gemm_t<<<g1, blk, 0, stream>>>(q, Wq, bq, qt);
    proj_gemm_t<<<g1, blk, 0, stream>>>(k, Wk, bk, kt);
    corr_fft_kernel<<<dim3(BB * HH * DEPTH), blk, 0, stream>>>(qt, kt);
    out_gemm<<<g1, blk, 0, stream>>>(kt, Wo, bo, out);
}

// Round 4
// 203.559 us; speedup vs baseline: 9.1396x; 3.0010x over previous
//
#include <hip/hip_runtime.h>
#include <hip/hip_fp16.h>
#include <float.h>
#include <math.h>

#define BB 8
#define LL 2048
#define NN 2048
#define DD 512
#define HH 8
#define DEPTH 64
#define TOPK 15
#define PIF 3.14159265358979323846f

using f16x8 = __attribute__((ext_vector_type(8))) _Float16;
typedef __attribute__((ext_vector_type(4))) float f32x4;
typedef __attribute__((ext_vector_type(8))) unsigned short us8;
typedef __attribute__((ext_vector_type(4))) unsigned short us4;

__device__ __forceinline__ unsigned short f2h(float f) {
    return __half_as_ushort(__float2half(f));  // RNE
}
__device__ __forceinline__ float2 cmul(float2 a, float2 b) {
    return make_float2(a.x * b.x - a.y * b.y, a.x * b.y + a.y * b.x);
}
__device__ __forceinline__ float2 cmulc(float2 a, float2 b) {  // a * conj(b)
    return make_float2(a.x * b.x + a.y * b.y, a.y * b.x - a.x * b.y);
}
__device__ __forceinline__ float2 cadd(float2 a, float2 b) { return make_float2(a.x + b.x, a.y + b.y); }
__device__ __forceinline__ float2 csub(float2 a, float2 b) { return make_float2(a.x - b.x, a.y - b.y); }

// ---------------- W transpose + fp32->fp16 convert (once per call) ----------------
// FIXED: p<4 (1024 float4 loads / 1024 us4 stores) covers the full 64x64 tile.
__global__ __launch_bounds__(256) void wt_convert(const float* __restrict__ Wq,
                                                  const float* __restrict__ Wk,
                                                  const float* __restrict__ Wo,
                                                  unsigned short* __restrict__ Tq,
                                                  unsigned short* __restrict__ Tk,
                                                  unsigned short* __restrict__ To) {
    __shared__ float T[64][65];
    const float* src = blockIdx.z == 0 ? Wq : (blockIdx.z == 1 ? Wk : Wo);
    unsigned short* dst = blockIdx.z == 0 ? Tq : (blockIdx.z == 1 ? Tk : To);
    const int tid = threadIdx.x;
    const int r0 = blockIdx.y * 64, c0 = blockIdx.x * 64;
#pragma unroll
    for (int p = 0; p < 4; ++p) {
        int idx = tid + 256 * p;          // [0,1024): row=idx>>4 in [0,64), c4=idx&15
        int row = idx >> 4, c4 = idx & 15;
        float4 v = *reinterpret_cast<const float4*>(&src[(size_t)(r0 + row) * DD + c0 + c4 * 4]);
        T[row][c4 * 4 + 0] = v.x;
        T[row][c4 * 4 + 1] = v.y;
        T[row][c4 * 4 + 2] = v.z;
        T[row][c4 * 4 + 3] = v.w;
    }
    __syncthreads();
#pragma unroll
    for (int p = 0; p < 4; ++p) {
        int idx = tid + 256 * p;
        int orow = idx >> 4, oc4 = idx & 15;
        us4 o;
#pragma unroll
        for (int j = 0; j < 4; ++j) o[j] = f2h(T[oc4 * 4 + j][orow]);
        *reinterpret_cast<us4*>(&dst[(size_t)(c0 + orow) * DD + r0 + oc4 * 4]) = o;
    }
}

// ---------------- projection GEMM, fp16 MFMA, output transposed [B,H,DEPTH,L] fp32 ----------------
// C[r,c] = sum_k X[r,k] W[k,c] + bias[c];  Wt[c][k] = W[k][c] (fp16 bits)
__global__ __launch_bounds__(256) void proj_gemm_mfma(const float* __restrict__ X,
                                                      const unsigned short* __restrict__ Wt,
                                                      const float* __restrict__ bias,
                                                      float* __restrict__ outT) {
    __shared__ unsigned short Asm[128][40];  // [m(row)][k] padded
    __shared__ unsigned short Bsm[128][40];  // [n(col)][k] padded
    const int tid = threadIdx.x;
    const int lane = tid & 63, wid = tid >> 6;
    const int wr = wid >> 1, wc = wid & 1;  // 2x2 wave grid
    const int g = lane >> 4, rl = lane & 15;
    const int r0 = blockIdx.y * 128, c0 = blockIdx.x * 128;
    f32x4 acc[4][4];
#pragma unroll
    for (int m = 0; m < 4; ++m)
#pragma unroll
        for (int n = 0; n < 4; ++n) acc[m][n] = (f32x4){0.f, 0.f, 0.f, 0.f};

    for (int k0 = 0; k0 < DD; k0 += 32) {
        // A tile: 128x32 fp32 -> fp16.  idx = tid + 256p: row=idx>>3, kq=idx&7
        float4 av[4];
#pragma unroll
        for (int p = 0; p < 4; ++p) {
            int idx = tid + 256 * p;
            int row = idx >> 3, kq = idx & 7;
            av[p] = *reinterpret_cast<const float4*>(&X[(size_t)(r0 + row) * DD + k0 + kq * 4]);
        }
        // B tile: 128x32 fp16 from Wt rows.  idx = tid + 256p: row=idx>>2, kq=idx&3
        us8 bv[2];
#pragma unroll
        for (int p = 0; p < 2; ++p) {
            int idx = tid + 256 * p;
            int row = idx >> 2, kq = idx & 3;
            bv[p] = *reinterpret_cast<const us8*>(&Wt[(size_t)(c0 + row) * DD + k0 + kq * 8]);
        }
        __syncthreads();  // previous iteration's fragment reads done
#pragma unroll
        for (int p = 0; p < 4; ++p) {
            int idx = tid + 256 * p;
            int row = idx >> 3, kq = idx & 7;
            us4 w;
            w[0] = f2h(av[p].x); w[1] = f2h(av[p].y); w[2] = f2h(av[p].z); w[3] = f2h(av[p].w);
            *reinterpret_cast<us4*>(&Asm[row][kq * 4]) = w;
        }
#pragma unroll
        for (int p = 0; p < 2; ++p) {
            int idx = tid + 256 * p;
            int row = idx >> 2, kq = idx & 3;
            *reinterpret_cast<us8*>(&Bsm[row][kq * 8]) = bv[p];
        }
        __syncthreads();
        f16x8 af[4], bfr[4];
#pragma unroll
        for (int m = 0; m < 4; ++m)
            af[m] = *reinterpret_cast<const f16x8*>(&Asm[wr * 64 + m * 16 + rl][g * 8]);
#pragma unroll
        for (int n = 0; n < 4; ++n)
            bfr[n] = *reinterpret_cast<const f16x8*>(&Bsm[wc * 64 + n * 16 + rl][g * 8]);
#pragma unroll
        for (int m = 0; m < 4; ++m)
#pragma unroll
            for (int n = 0; n < 4; ++n)
                acc[m][n] = __builtin_amdgcn_mfma_f32_16x16x32_f16(af[m], bfr[n], acc[m][n], 0, 0, 0);
    }

    // epilogue: transposed write outT[((b*8+h)*64+dd)*2048 + l], rows of C are l
    const int b = r0 >> 11, l0 = r0 & (LL - 1);
#pragma unroll
    for (int m = 0; m < 4; ++m) {
#pragma unroll
        for (int n = 0; n < 4; ++n) {
            int c = c0 + wc * 64 + n * 16 + rl;
            int h = c >> 6, dd = c & 63;
            float bvv = bias[c];
            int lb = l0 + wr * 64 + m * 16 + g * 4;
            float4 o = make_float4(acc[m][n][0] + bvv, acc[m][n][1] + bvv,
                                   acc[m][n][2] + bvv, acc[m][n][3] + bvv);
            *reinterpret_cast<float4*>(&outT[((size_t)(b * HH + h) * DEPTH + dd) * LL + lb]) = o;
        }
    }
}

// ---------------- correlation via FFT, SoA + quad passes + natural-order unpack ----------------
// reads qt,kt fp32 rows; writes delays as fp16 into kt row (first 4KB of each 8KB row)
__global__ __launch_bounds__(256) void corr_fft_v2(const float* __restrict__ qt,
                                                   float* __restrict__ kt) {
    __shared__ float zr[NN], zi[NN], q_s[NN];
    __shared__ float cand_v[64];
    __shared__ int cand_i[64];
    __shared__ float corr_s[TOPK];
    __shared__ int topi_s[TOPK];
    const int tid = threadIdx.x;
    const int lane = tid & 63, wid = tid >> 6;
    const size_t base = (size_t)blockIdx.x * NN;

#define LD2(i) make_float2(zr[i], zi[i])
#define ST2(i, v) do { zr[i] = (v).x; zi[i] = (v).y; } while (0)

    // ---- load 8 consecutive q,k per thread; scatter to bit-reversed slots; q_s natural ----
    {
        const float4* q4 = reinterpret_cast<const float4*>(qt + base);
        const float4* k4 = reinterpret_cast<const float4*>(kt + base);
        float4 qa = q4[2 * tid], qb = q4[2 * tid + 1];
        float4 ka = k4[2 * tid], kb = k4[2 * tid + 1];
        reinterpret_cast<float4*>(q_s)[2 * tid] = qa;
        reinterpret_cast<float4*>(q_s)[2 * tid + 1] = qb;
        int pb = (int)(__brev((unsigned)tid) >> 24);  // brev8(tid)
        const int b3[8] = {0, 4, 2, 6, 1, 5, 3, 7};   // brev3(u)
        float qv[8] = {qa.x, qa.y, qa.z, qa.w, qb.x, qb.y, qb.z, qb.w};
        float kv[8] = {ka.x, ka.y, ka.z, ka.w, kb.x, kb.y, kb.z, kb.w};
#pragma unroll
        for (int u = 0; u < 8; ++u) {
            int pf = b3[u] * 256 + pb;
            zr[pf] = qv[u];
            zi[pf] = kv[u];
        }
    }
    __syncthreads();

    // ---- forward DIT (bit-reversed in -> natural out), quad passes (h, 2h) ----
#pragma unroll
    for (int hh = 1; hh <= 256; hh <<= 2) {
#pragma unroll
        for (int i2 = 0; i2 < 2; ++i2) {
            int q = tid + 256 * i2;
            int p = q & (hh - 1);
            int e0 = ((q ^ p) << 2) | p;
            int e1 = e0 + hh, e2 = e0 + 2 * hh, e3 = e0 + 3 * hh;
            float2 a = LD2(e0), b = LD2(e1), c = LD2(e2), d = LD2(e3);
            float ang = -PIF * (float)p / (float)(2 * hh);
            float sn, cs;
            __sincosf(ang, &sn, &cs);
            float2 w2 = make_float2(cs, sn);
            float2 w1 = make_float2(cs * cs - sn * sn, 2.f * cs * sn);
            float2 bp = cmul(b, w1), dp = cmul(d, w1);
            float2 A0 = cadd(a, bp), A1 = csub(a, bp);
            float2 A2 = cadd(c, dp), A3 = csub(c, dp);
            float2 t2 = cmul(A2, w2);
            float2 u3 = cmul(A3, w2);
            float2 t3 = make_float2(u3.y, -u3.x);  // -i * u3
            ST2(e0, cadd(A0, t2));
            ST2(e2, csub(A0, t2));
            ST2(e1, cadd(A1, t3));
            ST2(e3, csub(A1, t3));
        }
        __syncthreads();
    }
    // single DIT stage h=1024
#pragma unroll
    for (int u = 0; u < 4; ++u) {
        int b4 = tid + 256 * u;
        float2 a = LD2(b4), c = LD2(b4 + 1024);
        float ang = -PIF * (float)b4 * (1.f / 1024.f);
        float sn, cs;
        __sincosf(ang, &sn, &cs);
        float2 t = cmul(c, make_float2(cs, sn));
        ST2(b4, cadd(a, t));
        ST2(b4 + 1024, csub(a, t));
    }
    __syncthreads();

    // ---- Hermitian unpack + S = Q*conj(K), NATURAL order (conflict-free) ----
    {
        float2 S[8];
#pragma unroll
        for (int u = 0; u < 8; ++u) {
            int f = tid + 256 * u;
            int mf = (NN - f) & (NN - 1);
            float2 Zf = LD2(f), Zm = LD2(mf);
            float2 Qf = make_float2(0.5f * (Zf.x + Zm.x), 0.5f * (Zf.y - Zm.y));
            float2 Dm = make_float2(Zf.x - Zm.x, Zf.y + Zm.y);   // Zf - conj(Zm)
            float2 Kf = make_float2(0.5f * Dm.y, -0.5f * Dm.x);  // -0.5i * Dm
            S[u] = cmulc(Qf, Kf);
        }
        __syncthreads();
#pragma unroll
        for (int u = 0; u < 8; ++u) ST2(tid + 256 * u, S[u]);
        __syncthreads();
    }

    // ---- inverse DIF (natural in -> bit-reversed out), quad passes (2h, h) ----
#pragma unroll
    for (int hh = 512; hh >= 2; hh >>= 2) {
#pragma unroll
        for (int i2 = 0; i2 < 2; ++i2) {
            int q = tid + 256 * i2;
            int p = q & (hh - 1);
            int e0 = ((q ^ p) << 2) | p;
            int e1 = e0 + hh, e2 = e0 + 2 * hh, e3 = e0 + 3 * hh;
            float2 a = LD2(e0), b = LD2(e1), c = LD2(e2), d = LD2(e3);
            float ang = PIF * (float)p / (float)(2 * hh);
            float sn, cs;
            __sincosf(ang, &sn, &cs);
            float2 w = make_float2(cs, sn);
            float2 w2 = make_float2(cs * cs - sn * sn, 2.f * cs * sn);
            float2 S0 = cadd(a, c);
            float2 D0 = cmul(csub(a, c), w);
            float2 S1 = cadd(b, d);
            float2 f2 = cmul(csub(b, d), w);
            float2 D1 = make_float2(-f2.y, f2.x);  // i * f2
            ST2(e0, cadd(S0, S1));
            ST2(e1, cmul(csub(S0, S1), w2));
            ST2(e2, cadd(D0, D1));
            ST2(e3, cmul(csub(D0, D1), w2));
        }
        __syncthreads();
    }
    // final DIF stage h=1 into registers; real part only.  tau = brev of storage idx.
    float r[8];
    int tau[8];
#pragma unroll
    for (int u = 0; u < 4; ++u) {
        int b4 = tid + 256 * u;
        float x0 = zr[2 * b4], x1 = zr[2 * b4 + 1];
        r[u] = (x0 + x1) * (1.0f / NN);
        r[u + 4] = (x0 - x1) * (1.0f / NN);
        int t0 = (int)(__brev((unsigned)b4) >> 22);  // brev10
        tau[u] = t0;
        tau[u + 4] = t0 + 1024;
    }

    // ---- per-wave top-15 (shfl only), then single merge ----
    for (int it = 0; it < TOPK; ++it) {
        float best = -FLT_MAX;
        int bi = 0x7fffffff;
#pragma unroll
        for (int w = 0; w < 8; ++w) {
            if (r[w] > best || (r[w] == best && tau[w] < bi)) { best = r[w]; bi = tau[w]; }
        }
#pragma unroll
        for (int off = 32; off >= 1; off >>= 1) {
            float ov = __shfl_xor(best, off);
            int oi = __shfl_xor(bi, off);
            if (ov > best || (ov == best && oi < bi)) { best = ov; bi = oi; }
        }
        if (lane == 0) { cand_v[wid * 16 + it] = best; cand_i[wid * 16 + it] = bi; }
#pragma unroll
        for (int w = 0; w < 8; ++w)
            if (tau[w] == bi) r[w] = -FLT_MAX;
    }
    __syncthreads();
    if (tid == 0) {
        int head[4] = {0, 0, 0, 0};
        float w15[TOPK];
        int i15[TOPK];
        for (int it = 0; it < TOPK; ++it) {
            float bw = -FLT_MAX;
            int bi = 0x7fffffff, bs = 0;
            for (int s = 0; s < 4; ++s) {
                if (head[s] < TOPK) {
                    float v = cand_v[s * 16 + head[s]];
                    int ii = cand_i[s * 16 + head[s]];
                    if (v > bw || (v == bw && ii < bi)) { bw = v; bi = ii; bs = s; }
                }
            }
            head[bs]++;
            w15[it] = bw;
            i15[it] = bi;
        }
        float m = w15[0];
        for (int i = 1; i < TOPK; ++i) m = fmaxf(m, w15[i]);
        float ssum = 0.f;
        for (int i = 0; i < TOPK; ++i) {
            float e = expf(w15[i] - m);
            corr_s[i] = e;
            ssum += e;
        }
        float inv = 1.f / ssum;
        for (int i = 0; i < TOPK; ++i) { corr_s[i] *= inv; topi_s[i] = i15[i]; }
    }
    __syncthreads();

    // ---- aggregation; write fp16 delays in-place into kt row (stride 4096 ushort per row) ----
    float cw[TOPK];
    int ci[TOPK];
#pragma unroll
    for (int i = 0; i < TOPK; ++i) { cw[i] = corr_s[i]; ci[i] = topi_s[i]; }
    unsigned short* db = reinterpret_cast<unsigned short*>(kt) + base * 2;
#pragma unroll
    for (int u = 0; u < 8; ++u) {
        int t = tid + 256 * u;
        float acc = 0.f;
#pragma unroll
        for (int i = 0; i < TOPK; ++i) acc += cw[i] * q_s[(t + ci[i]) & (NN - 1)];
        db[t] = f2h(acc);
    }
#undef LD2
#undef ST2
}

// ---------------- output GEMM, fp16 MFMA: out[r,c] = sum_k delays[b,k,l]*Wo[k,c] + bo[c] ----------------
// delays fp16 rows at ((ushort*)kt) + (b*512+k)*4096;  WtO[c][k] = Wo[k][c]
__global__ __launch_bounds__(256) void out_gemm_mfma(const float* __restrict__ ktbuf,
                                                     const unsigned short* __restrict__ WtO,
                                                     const float* __restrict__ bias,
                                                     float* __restrict__ out) {
    __shared__ unsigned short Asm[32][128];  // [k][l] linear
    __shared__ unsigned short Bsm[128][40];  // [c][k] padded
    const unsigned short* db = reinterpret_cast<const unsigned short*>(ktbuf);
    const int tid = threadIdx.x;
    const int lane = tid & 63, wid = tid >> 6;
    const int wr = wid >> 1, wc = wid & 1;
    const int g = lane >> 4, rl = lane & 15;
    const int r0 = blockIdx.y * 128, c0 = blockIdx.x * 128;
    const int b = r0 >> 11, l0 = r0 & (LL - 1);
    f32x4 acc[4][4];
#pragma unroll
    for (int m = 0; m < 4; ++m)
#pragma unroll
        for (int n = 0; n < 4; ++n) acc[m][n] = (f32x4){0.f, 0.f, 0.f, 0.f};

    for (int k0 = 0; k0 < DD; k0 += 32) {
        us8 avv[2], bvv[2];
#pragma unroll
        for (int p = 0; p < 2; ++p) {
            int idx = tid + 256 * p;
            int kr = idx >> 4, dc = idx & 15;
            avv[p] = *reinterpret_cast<const us8*>(
                &db[(size_t)(b * DD + k0 + kr) * 4096 + l0 + dc * 8]);
        }
#pragma unroll
        for (int p = 0; p < 2; ++p) {
            int idx = tid + 256 * p;
            int row = idx >> 2, kq = idx & 3;
            bvv[p] = *reinterpret_cast<const us8*>(&WtO[(size_t)(c0 + row) * DD + k0 + kq * 8]);
        }
        __syncthreads();
#pragma unroll
        for (int p = 0; p < 2; ++p) {
            int idx = tid + 256 * p;
            int kr = idx >> 4, dc = idx & 15;
            *reinterpret_cast<us8*>(&Asm[kr][dc * 8]) = avv[p];
        }
#pragma unroll
        for (int p = 0; p < 2; ++p) {
            int idx = tid + 256 * p;
            int row = idx >> 2, kq = idx & 3;
            *reinterpret_cast<us8*>(&Bsm[row][kq * 8]) = bvv[p];
        }
        __syncthreads();
        f16x8 af[4], bfr[4];
#pragma unroll
        for (int m = 0; m < 4; ++m) {
            int l = wr * 64 + m * 16 + rl;
            us8 t;
#pragma unroll
            for (int j = 0; j < 8; ++j) t[j] = Asm[g * 8 + j][l];
            af[m] = __builtin_bit_cast(f16x8, t);
        }
#pragma unroll
        for (int n = 0; n < 4; ++n)
            bfr[n] = *reinterpret_cast<const f16x8*>(&Bsm[wc * 64 + n * 16 + rl][g * 8]);
#pragma unroll
        for (int m = 0; m < 4; ++m)
#pragma unroll
            for (int n = 0; n < 4; ++n)
                acc[m][n] = __builtin_amdgcn_mfma_f32_16x16x32_f16(af[m], bfr[n], acc[m][n], 0, 0, 0);
    }

#pragma unroll
    for (int m = 0; m < 4; ++m) {
#pragma unroll
        for (int n = 0; n < 4; ++n) {
            int c = c0 + wc * 64 + n * 16 + rl;
            float bvv = bias[c];
            int rbase = r0 + wr * 64 + m * 16 + g * 4;
#pragma unroll
            for (int j = 0; j < 4; ++j)
                out[(size_t)(rbase + j) * DD + c] = acc[m][n][j] + bvv;
        }
    }
}

extern "C" void kernel_launch(void* const* d_in, const int* in_sizes, int n_in,
                              void* d_out, int out_size, void* d_ws, size_t ws_size,
                              hipStream_t stream) {
    const float* q = (const float*)d_in[0];
    const float* k = (const float*)d_in[1];
    const float* Wq = (const float*)d_in[3];
    const float* bq = (const float*)d_in[4];
    const float* Wk = (const float*)d_in[5];
    const float* bk = (const float*)d_in[6];
    const float* Wo = (const float*)d_in[9];
    const float* bo = (const float*)d_in[10];
    float* out = (float*)d_out;

    float* qt = (float*)d_ws;                           // [B,H,DEPTH,L] fp32, 33.5MB
    float* kt = qt + (size_t)BB * HH * DEPTH * LL;      // [B,H,DEPTH,L] fp32; delays fp16 in-place
    unsigned short* Tq = (unsigned short*)(kt + (size_t)BB * HH * DEPTH * LL);
    unsigned short* Tk = Tq + (size_t)DD * DD;
    unsigned short* To = Tk + (size_t)DD * DD;

    dim3 blk(256);
    wt_convert<<<dim3(8, 8, 3), blk, 0, stream>>>(Wq, Wk, Wo, Tq, Tk, To);
    proj_gemm_mfma<<<dim3(4, 128), blk, 0, stream>>>(q, Tq, bq, qt);
    proj_gemm_mfma<<<dim3(4, 128), blk, 0, stream>>>(k, Tk, bk, kt);
    corr_fft_v2<<<dim3(BB * HH * DEPTH), blk, 0, stream>>>(qt, kt);
    out_gemm_mfma<<<dim3(4, 128), blk, 0, stream>>>(kt, To, bo, out);
}